// Round 8
// baseline (874.612 us; speedup 1.0000x reference)
//
#include <hip/hip_runtime.h>

constexpr int Bc = 8, Hc = 16, Sc = 4096, Dc = 64;
constexpr int BH = Bc * Hc;               // 128
constexpr int SS = 8;                     // s-split chunks in k1
constexpr int CHUNK = Sc / SS;            // 512 rows per block
constexpr int STG = 16;                   // rows staged per step
constexpr int NST = CHUNK / STG;          // 32 stages
constexpr int MM = Dc * Dc;               // 4096 floats of M per (bh)
constexpr int NZP = SS * 4;               // 32 z partials (per-wave)
constexpr int QT = 128;                   // q-rows per block in k3

// ---- Kernel 1: barrier-free pipelined outer product ----
// Wave w owns LDS rows [w*4, w*4+4) for loads, writes, reads, and z — waves are
// fully independent, so NO per-stage __syncthreads (no vmcnt(0) drains).
// Prefetch 3 stages ahead (4 static reg sets) -> ~1024 cyc coverage > HBM latency.
__global__ __launch_bounds__(256, 4) void k1_accum(const float* __restrict__ K,
                                                   const float* __restrict__ V,
                                                   float* __restrict__ Pm,
                                                   double* __restrict__ Pz) {
  const int blk = blockIdx.x;
  const int bh = blk >> 3;       // 0..127
  const int ck = blk & 7;        // 0..7
  const int tid = threadIdx.x;
  const int w = tid >> 6;        // wave 0..3
  const int l = tid & 63;
  const int d0 = (l >> 3) * 8;   // k-dim tile base
  const int e0 = (l & 7) * 8;    // v-dim tile base

  const size_t base = ((size_t)bh * Sc + (size_t)ck * CHUNK) * Dc;
  const float4* gk4 = (const float4*)(K + base);
  const float4* gv4 = (const float4*)(V + base);

  // staging: lk[2][16][64] at smem[buf*1024]; lv[2][16][64] at smem[2048+buf*1024]
  __shared__ __align__(16) float smem[4096];   // 16 KB (reused for combine)

  const int srow = tid >> 4;           // 0..15; wave w -> rows w*4..w*4+3
  const int scol = (tid & 15) * 4;

  float acc[8][8] = {};
  double zacc = 0.0;

  // 4 static prefetch sets; set (s & 3) holds stage-s data
  float4 pk0, pk1, pk2, pk3, pv0, pv1, pv2, pv3;

  // prologue: stages 0,1,2 -> sets 0,1,2; stage 0 into LDS buf 0
  pk0 = gk4[tid];        pv0 = gv4[tid];
  pk1 = gk4[256 + tid];  pv1 = gv4[256 + tid];
  pk2 = gk4[512 + tid];  pv2 = gv4[512 + tid];
  *(float4*)&smem[srow * 64 + scol] = pk0;
  *(float4*)&smem[2048 + srow * 64 + scol] = pv0;

  // Per stage st: load stage st+3 -> set (st+3)&3; LDS-write set (st+1)&3 into
  // buf (st+1)&1; compute from buf st&1. All set indices compile-time static.
#define K1_STAGE(STC, PKL, PVL, PKW, PVW)                                   \
  {                                                                         \
    const int st_ = (STC);                                                  \
    if (st_ + 3 < NST) {                                                    \
      PKL = gk4[(st_ + 3) * 256 + tid];                                     \
      PVL = gv4[(st_ + 3) * 256 + tid];                                     \
    }                                                                       \
    if (st_ + 1 < NST) {                                                    \
      const int nb = (st_ + 1) & 1;                                         \
      *(float4*)&smem[nb * 1024 + srow * 64 + scol] = PKW;                  \
      *(float4*)&smem[2048 + nb * 1024 + srow * 64 + scol] = PVW;           \
    }                                                                       \
    const float* lkc = &smem[(st_ & 1) * 1024];                             \
    const float* lvc = &smem[2048 + (st_ & 1) * 1024];                      \
    _Pragma("unroll")                                                       \
    for (int r = 0; r < 4; ++r) {                                           \
      const int row = w * 4 + r;                                            \
      const float4 ka = *(const float4*)&lkc[row * 64 + d0];                \
      const float4 kb = *(const float4*)&lkc[row * 64 + d0 + 4];            \
      const float4 va = *(const float4*)&lvc[row * 64 + e0];                \
      const float4 vb = *(const float4*)&lvc[row * 64 + e0 + 4];            \
      const float kk[8] = {ka.x, ka.y, ka.z, ka.w, kb.x, kb.y, kb.z, kb.w}; \
      const float vv[8] = {va.x, va.y, va.z, va.w, vb.x, vb.y, vb.z, vb.w}; \
      _Pragma("unroll")                                                     \
      for (int a = 0; a < 8; ++a)                                           \
        _Pragma("unroll")                                                   \
        for (int b = 0; b < 8; ++b)                                         \
          acc[a][b] = fmaf(kk[a], vv[b], acc[a][b]);                        \
      zacc += (double)lkc[row * 64 + l];                                    \
    }                                                                       \
  }

  for (int stb = 0; stb < NST; stb += 4) {
    K1_STAGE(stb + 0, pk3, pv3, pk1, pv1)   // st%4==0: load set3, write set1
    K1_STAGE(stb + 1, pk0, pv0, pk2, pv2)   // st%4==1: load set0, write set2
    K1_STAGE(stb + 2, pk1, pv1, pk3, pv3)   // st%4==2: load set1, write set3
    K1_STAGE(stb + 3, pk2, pv2, pk0, pv0)   // st%4==3: load set2, write set0
  }
#undef K1_STAGE

  __syncthreads();   // all waves done streaming; smem now reused for combine

  // combine 4 wave-partials of M in smem: order ((p0+p1)+p2)+p3
  #pragma unroll
  for (int p = 0; p < 4; ++p) {
    if (w == p) {
      #pragma unroll
      for (int a = 0; a < 8; ++a) {
        float* dst = &smem[(d0 + a) * 64 + e0];
        float4 lo = make_float4(acc[a][0], acc[a][1], acc[a][2], acc[a][3]);
        float4 hi = make_float4(acc[a][4], acc[a][5], acc[a][6], acc[a][7]);
        if (p == 0) {
          *(float4*)dst = lo; *(float4*)(dst + 4) = hi;
        } else {
          float4 olo = *(float4*)dst, ohi = *(float4*)(dst + 4);
          olo.x += lo.x; olo.y += lo.y; olo.z += lo.z; olo.w += lo.w;
          ohi.x += hi.x; ohi.y += hi.y; ohi.z += hi.z; ohi.w += hi.w;
          *(float4*)dst = olo; *(float4*)(dst + 4) = ohi;
        }
      }
    }
    __syncthreads();
  }

  // coalesced Pm write from smem
  float* pd = Pm + ((size_t)ck * BH + bh) * MM;
  #pragma unroll
  for (int j = 0; j < 4; ++j) {
    const int idx = tid + j * 256;
    ((float4*)pd)[idx] = *(const float4*)&smem[idx * 4];
  }
  Pz[((size_t)(ck * 4 + w) * BH + bh) * Dc + l] = zacc;
}

// ---- Kernel 2: reduce M partials (f32); z = f64 exact sum ROUNDED TO F32 ----
__global__ __launch_bounds__(256) void k2_reduce(const float* __restrict__ Pm,
                                                 const double* __restrict__ Pz,
                                                 float* __restrict__ Fm,
                                                 float* __restrict__ Fz) {
  const int i = blockIdx.x * 256 + threadIdx.x;
  const int nm = BH * MM;
  if (i < nm) {
    float s = 0.f;
    #pragma unroll
    for (int c = 0; c < SS; ++c) s += Pm[(size_t)c * nm + i];
    Fm[i] = s;
  }
  const int nz = BH * Dc;
  if (i < nz) {
    double s = 0.0;
    #pragma unroll
    for (int c = 0; c < NZP; ++c) s += Pz[(size_t)c * nz + i];
    Fz[i] = (float)s;   // f32 intermediate matches np bitwise
  }
}

// ---- Kernel 3: out = (q @ M) / (q . z_f32 + eps); 4 rows x 8 cols per thread ----
__global__ __launch_bounds__(256) void k3_retrieve(const float* __restrict__ Q,
                                                   const float* __restrict__ Fm,
                                                   const float* __restrict__ Fz,
                                                   float* __restrict__ O) {
  const int blk = blockIdx.x;             // BH * (Sc/QT) = 128*32
  const int bh = blk >> 5;
  const int row0 = (blk & 31) * QT;

  __shared__ __align__(16) float lm[Dc][Dc];     // 16 KB
  __shared__ __align__(16) float lq[QT][68];     // padded: row stride 68 floats
  __shared__ __align__(16) float lz[Dc];         // f32 z (the np intermediate)

  const int tid = threadIdx.x;

  // stage M: contiguous 16 KB
  const float4* gm4 = (const float4*)(Fm + (size_t)bh * MM);
  float4* lm4 = (float4*)&lm[0][0];
  #pragma unroll
  for (int j = 0; j < 4; ++j) lm4[tid + j * 256] = gm4[tid + j * 256];
  if (tid < Dc) lz[tid] = Fz[(size_t)bh * Dc + tid];

  // stage q rows (coalesced global, padded LDS rows)
  const float4* gq4 = (const float4*)(Q + ((size_t)bh * Sc + row0) * Dc);
  #pragma unroll
  for (int j = 0; j < 8; ++j) {
    const int i4 = tid + j * 256;
    const float4 v = gq4[i4];
    const int f = i4 * 4;
    *(float4*)&lq[f >> 6][f & 63] = v;
  }
  __syncthreads();

  const int rg = tid >> 3;       // 0..31 -> row quad
  const int cg = tid & 7;        // 0..7  -> 8-col block
  const int r0 = rg * 4;
  const int e0 = cg * 8;

  float acc[4][8] = {};
  double den[4] = {0.0, 0.0, 0.0, 0.0};

  #pragma unroll
  for (int ds = 0; ds < 16; ++ds) {
    const int d0 = ds * 4;
    const float4 z4 = *(const float4*)&lz[d0];
    const float* zf = (const float*)&z4;
    float4 q4[4];
    #pragma unroll
    for (int r = 0; r < 4; ++r) q4[r] = *(const float4*)&lq[r0 + r][d0];
    const float* qf[4] = {(const float*)&q4[0], (const float*)&q4[1],
                          (const float*)&q4[2], (const float*)&q4[3]};
    #pragma unroll
    for (int i = 0; i < 4; ++i) {
      const float4 ma = *(const float4*)&lm[d0 + i][e0];
      const float4 mb = *(const float4*)&lm[d0 + i][e0 + 4];
      const float mf[8] = {ma.x, ma.y, ma.z, ma.w, mb.x, mb.y, mb.z, mb.w};
      const double zd = (double)zf[i];
      #pragma unroll
      for (int r = 0; r < 4; ++r) {
        const float qs = qf[r][i];
        den[r] += (double)qs * zd;
        #pragma unroll
        for (int j = 0; j < 8; ++j)
          acc[r][j] = fmaf(qs, mf[j], acc[r][j]);
      }
    }
  }

  #pragma unroll
  for (int r = 0; r < 4; ++r) {
    const double iv = 1.0 / (den[r] + 1e-6);
    float* go = O + ((size_t)bh * Sc + row0 + r0 + r) * Dc + e0;
    ((float4*)go)[0] = make_float4((float)((double)acc[r][0] * iv),
                                   (float)((double)acc[r][1] * iv),
                                   (float)((double)acc[r][2] * iv),
                                   (float)((double)acc[r][3] * iv));
    ((float4*)go)[1] = make_float4((float)((double)acc[r][4] * iv),
                                   (float)((double)acc[r][5] * iv),
                                   (float)((double)acc[r][6] * iv),
                                   (float)((double)acc[r][7] * iv));
  }
}

extern "C" void kernel_launch(void* const* d_in, const int* in_sizes, int n_in,
                              void* d_out, int out_size, void* d_ws, size_t ws_size,
                              hipStream_t stream) {
  const float* K = (const float*)d_in[0];   // keys    [B,H,S,D]
  const float* V = (const float*)d_in[1];   // values
  const float* Q = (const float*)d_in[2];   // queries
  float* O = (float*)d_out;                 // [B,H,S,D]

  float* Pm = (float*)d_ws;                                  // SS*BH*MM floats  (16.8 MB)
  float* Fm = Pm + (size_t)SS * BH * MM;                     // BH*MM floats     (2.1 MB)
  double* Pz = (double*)(Fm + (size_t)BH * MM);              // NZP*BH*Dc doubles (2.1 MB)
  float* Fz = (float*)(Pz + (size_t)NZP * BH * Dc);          // BH*Dc floats     (32 KB)

  hipLaunchKernelGGL(k1_accum, dim3(BH * SS), dim3(256), 0, stream, K, V, Pm, Pz);
  hipLaunchKernelGGL(k2_reduce, dim3((BH * MM + 255) / 256), dim3(256), 0, stream, Pm, Pz, Fm, Fz);
  hipLaunchKernelGGL(k3_retrieve, dim3(BH * (Sc / QT)), dim3(256), 0, stream, Q, Fm, Fz, O);
}

// Round 9
// 173.537 us; speedup vs baseline: 5.0399x; 5.0399x over previous
//
#include <hip/hip_runtime.h>

constexpr int Sc = 4096, Dc = 64;
constexpr int BH = 128;
constexpr int SS = 8;                     // s-split chunks in k1
constexpr int CHUNK = Sc / SS;            // 512 rows per block
constexpr int SROWS = 32;                 // s-rows per stage (one MFMA K-step)
constexpr int NST = CHUNK / SROWS;        // 16 stages
constexpr int MM = Dc * Dc;               // 4096 floats of M per (bh)
constexpr int LSTR = 66;                  // bf16 elems per LDS row (pad 2: bank spread)
constexpr int NZC = SS * SROWS;           // 256 z partial groups
constexpr int QT = 128;                   // q-rows per block in k3

using sh8 = __attribute__((ext_vector_type(8))) short;
using f32x4 = __attribute__((ext_vector_type(4))) float;

__device__ __forceinline__ unsigned int packbf2(float lo, float hi) {
  // two RNE float->bf16 packed into one dword
  unsigned int a = __builtin_bit_cast(unsigned int, lo);
  unsigned int b = __builtin_bit_cast(unsigned int, hi);
  a = (a + 0x7fffu + ((a >> 16) & 1u)) >> 16;
  b = (b + 0x7fffu + ((b >> 16) & 1u)) & 0xffff0000u;
  return a | b;
}

// ---- Kernel 1: M = K^T V per (bh,chunk) via bf16 MFMA; z exact f64 from fp32 regs ----
// 4 waves: wave w owns output d-rows [16w,16w+16), loops 4 e-tiles.
// LDS: row-major [32 s][66] bf16 tiles for K and V, double-buffered.
__global__ __launch_bounds__(256) void k1_accum(const float* __restrict__ K,
                                                const float* __restrict__ V,
                                                float* __restrict__ Pm,
                                                double* __restrict__ Pz) {
  const int blk = blockIdx.x, bh = blk >> 3, ck = blk & 7;
  const int tid = threadIdx.x, w = tid >> 6, l = tid & 63;
  const int g = l >> 4, c = l & 15;
  const int s_l = tid >> 3, dblk = tid & 7;     // staging: row s_l, floats d=8*dblk..+7

  const size_t base = ((size_t)bh * Sc + (size_t)ck * CHUNK) * Dc;
  const float4* gk4 = (const float4*)(K + base);
  const float4* gv4 = (const float4*)(V + base);
  const int ldi = s_l * 16 + dblk * 2;          // float4 index within a 32-row stage

  __shared__ __align__(16) unsigned short lk[2][SROWS * LSTR];
  __shared__ __align__(16) unsigned short lv[2][SROWS * LSTR];

  f32x4 acc[4];
  #pragma unroll
  for (int i = 0; i < 4; ++i) acc[i] = (f32x4){0.f, 0.f, 0.f, 0.f};
  double zacc[8] = {};

  float4 ka, kb, va, vb;

#define K1_STAGEWRITE(BUF)                                                   \
  {                                                                          \
    unsigned int* dk = (unsigned int*)&lk[BUF][s_l * LSTR + dblk * 8];       \
    dk[0] = packbf2(ka.x, ka.y); dk[1] = packbf2(ka.z, ka.w);                \
    dk[2] = packbf2(kb.x, kb.y); dk[3] = packbf2(kb.z, kb.w);                \
    unsigned int* dv = (unsigned int*)&lv[BUF][s_l * LSTR + dblk * 8];       \
    dv[0] = packbf2(va.x, va.y); dv[1] = packbf2(va.z, va.w);                \
    dv[2] = packbf2(vb.x, vb.y); dv[3] = packbf2(vb.z, vb.w);                \
    zacc[0] += (double)ka.x; zacc[1] += (double)ka.y;                        \
    zacc[2] += (double)ka.z; zacc[3] += (double)ka.w;                        \
    zacc[4] += (double)kb.x; zacc[5] += (double)kb.y;                        \
    zacc[6] += (double)kb.z; zacc[7] += (double)kb.w;                        \
  }

  // prologue: stage 0
  ka = gk4[ldi]; kb = gk4[ldi + 1]; va = gv4[ldi]; vb = gv4[ldi + 1];
  K1_STAGEWRITE(0)
  __syncthreads();

  for (int st = 0; st < NST; ++st) {
    const int cur = st & 1;
    if (st + 1 < NST) {                 // issue next-stage global loads early
      const int o = (st + 1) * (SROWS * 16);
      ka = gk4[o + ldi]; kb = gk4[o + ldi + 1];
      va = gv4[o + ldi]; vb = gv4[o + ldi + 1];
    }
    // fragments: k-contiguous per lane (A row=c -> d=16w+c; B col=c -> e=16et+c)
    const unsigned short* plk = lk[cur];
    const unsigned short* plv = lv[cur];
    sh8 afr;
    #pragma unroll
    for (int j = 0; j < 8; ++j)
      afr[j] = (short)plk[(8 * g + j) * LSTR + 16 * w + c];
    #pragma unroll
    for (int et = 0; et < 4; ++et) {
      sh8 bfr;
      #pragma unroll
      for (int j = 0; j < 8; ++j)
        bfr[j] = (short)plv[(8 * g + j) * LSTR + 16 * et + c];
      acc[et] = __builtin_amdgcn_mfma_f32_16x16x32_bf16(afr, bfr, acc[et], 0, 0, 0);
    }
    if (st + 1 < NST) {
      K1_STAGEWRITE((st + 1) & 1)       // write late; z accumulated here once/stage
    }
    __syncthreads();
  }
#undef K1_STAGEWRITE

  // Pm partial: D layout col=lane&15, row=(lane>>4)*4+reg
  float* pd = Pm + ((size_t)ck * BH + bh) * MM;
  #pragma unroll
  for (int et = 0; et < 4; ++et)
    #pragma unroll
    for (int r = 0; r < 4; ++r)
      pd[(16 * w + 4 * g + r) * 64 + 16 * et + c] = acc[et][r];

  // z partials: group = ck*32 + s_l, cols d = 8*dblk..+7
  double* pz = Pz + ((size_t)ck * SROWS + s_l) * (size_t)(BH * 64) +
               (size_t)bh * 64 + dblk * 8;
  #pragma unroll
  for (int j = 0; j < 8; ++j) pz[j] = zacc[j];
}

// ---- Kernel 2: reduce M partials (f32); z = f64 exact sum ROUNDED TO F32 ----
__global__ __launch_bounds__(256) void k2_reduce(const float* __restrict__ Pm,
                                                 const double* __restrict__ Pz,
                                                 float* __restrict__ Fm,
                                                 float* __restrict__ Fz) {
  const int i = blockIdx.x * 256 + threadIdx.x;
  const int nm = BH * MM;
  if (i < nm) {
    float s = 0.f;
    #pragma unroll
    for (int cc = 0; cc < SS; ++cc) s += Pm[(size_t)cc * nm + i];
    Fm[i] = s;
  }
  const int nz = BH * Dc;
  if (i < nz) {
    double s = 0.0;
    for (int cc = 0; cc < NZC; ++cc) s += Pz[(size_t)cc * nz + i];
    Fz[i] = (float)s;   // f32 intermediate matches np bitwise
  }
}

// ---- Kernel 3: out = (q @ M) / (q . z_f32 + eps); 4 rows x 8 cols per thread ----
__global__ __launch_bounds__(256) void k3_retrieve(const float* __restrict__ Q,
                                                   const float* __restrict__ Fm,
                                                   const float* __restrict__ Fz,
                                                   float* __restrict__ O) {
  const int blk = blockIdx.x;             // BH * (Sc/QT) = 128*32
  const int bh = blk >> 5;
  const int row0 = (blk & 31) * QT;

  __shared__ __align__(16) float lm[Dc][Dc];     // 16 KB
  __shared__ __align__(16) float lq[QT][68];     // padded: row stride 68 floats
  __shared__ __align__(16) float lz[Dc];         // f32 z (the np intermediate)

  const int tid = threadIdx.x;

  // stage M: contiguous 16 KB
  const float4* gm4 = (const float4*)(Fm + (size_t)bh * MM);
  float4* lm4 = (float4*)&lm[0][0];
  #pragma unroll
  for (int j = 0; j < 4; ++j) lm4[tid + j * 256] = gm4[tid + j * 256];
  if (tid < Dc) lz[tid] = Fz[(size_t)bh * Dc + tid];

  // stage q rows (coalesced global, padded LDS rows)
  const float4* gq4 = (const float4*)(Q + ((size_t)bh * Sc + row0) * Dc);
  #pragma unroll
  for (int j = 0; j < 8; ++j) {
    const int i4 = tid + j * 256;
    const float4 v = gq4[i4];
    const int f = i4 * 4;
    *(float4*)&lq[f >> 6][f & 63] = v;
  }
  __syncthreads();

  const int rg = tid >> 3;       // 0..31 -> row quad
  const int cg = tid & 7;        // 0..7  -> 8-col block
  const int r0 = rg * 4;
  const int e0 = cg * 8;

  float acc[4][8] = {};
  double den[4] = {0.0, 0.0, 0.0, 0.0};

  #pragma unroll
  for (int ds = 0; ds < 16; ++ds) {
    const int d0 = ds * 4;
    const float4 z4 = *(const float4*)&lz[d0];
    const float* zf = (const float*)&z4;
    float4 q4[4];
    #pragma unroll
    for (int r = 0; r < 4; ++r) q4[r] = *(const float4*)&lq[r0 + r][d0];
    const float* qf[4] = {(const float*)&q4[0], (const float*)&q4[1],
                          (const float*)&q4[2], (const float*)&q4[3]};
    #pragma unroll
    for (int i = 0; i < 4; ++i) {
      const float4 ma = *(const float4*)&lm[d0 + i][e0];
      const float4 mb = *(const float4*)&lm[d0 + i][e0 + 4];
      const float mf[8] = {ma.x, ma.y, ma.z, ma.w, mb.x, mb.y, mb.z, mb.w};
      const double zd = (double)zf[i];
      #pragma unroll
      for (int r = 0; r < 4; ++r) {
        const float qs = qf[r][i];
        den[r] += (double)qs * zd;
        #pragma unroll
        for (int j = 0; j < 8; ++j)
          acc[r][j] = fmaf(qs, mf[j], acc[r][j]);
      }
    }
  }

  #pragma unroll
  for (int r = 0; r < 4; ++r) {
    const double iv = 1.0 / (den[r] + 1e-6);
    float* go = O + ((size_t)bh * Sc + row0 + r0 + r) * Dc + e0;
    ((float4*)go)[0] = make_float4((float)((double)acc[r][0] * iv),
                                   (float)((double)acc[r][1] * iv),
                                   (float)((double)acc[r][2] * iv),
                                   (float)((double)acc[r][3] * iv));
    ((float4*)go)[1] = make_float4((float)((double)acc[r][4] * iv),
                                   (float)((double)acc[r][5] * iv),
                                   (float)((double)acc[r][6] * iv),
                                   (float)((double)acc[r][7] * iv));
  }
}

extern "C" void kernel_launch(void* const* d_in, const int* in_sizes, int n_in,
                              void* d_out, int out_size, void* d_ws, size_t ws_size,
                              hipStream_t stream) {
  const float* K = (const float*)d_in[0];   // keys    [B,H,S,D]
  const float* V = (const float*)d_in[1];   // values
  const float* Q = (const float*)d_in[2];   // queries
  float* O = (float*)d_out;                 // [B,H,S,D]

  float* Pm = (float*)d_ws;                                  // SS*BH*MM floats   (16.8 MB)
  float* Fm = Pm + (size_t)SS * BH * MM;                     // BH*MM floats      (2.1 MB)
  double* Pz = (double*)(Fm + (size_t)BH * MM);              // NZC*BH*Dc doubles (16.8 MB)
  float* Fz = (float*)(Pz + (size_t)NZC * BH * Dc);          // BH*Dc floats      (32 KB)

  hipLaunchKernelGGL(k1_accum, dim3(BH * SS), dim3(256), 0, stream, K, V, Pm, Pz);
  hipLaunchKernelGGL(k2_reduce, dim3((BH * MM + 255) / 256), dim3(256), 0, stream, Pm, Pz, Fm, Fz);
  hipLaunchKernelGGL(k3_retrieve, dim3(BH * (Sc / QT)), dim3(256), 0, stream, Q, Fm, Fz, O);
}